// Round 7
// baseline (324.045 us; speedup 1.0000x reference)
//
#include <hip/hip_runtime.h>

#define NBATCH 4
#define NN 2048
#define NR 8192            // NBATCH*NN rows
#define TOPK 10
#define CSTRIDE 321        // cand row stride in words (odd -> conflict-free)

typedef __attribute__((ext_vector_type(16))) float f32x16;
typedef __attribute__((ext_vector_type(8))) short bf16x8;

__device__ inline unsigned short f2bf(float x) {
    unsigned u = __float_as_uint(x);
    unsigned r = (u + 0x7FFF + ((u >> 16) & 1)) >> 16;
    return (unsigned short)r;
}

// ---------------- K13: heterogeneous fusion of encoder + base-writer --------
// blocks 0..2047: k1 encoder (latency/VALU-bound, ~0 HBM) -- dispatched FIRST
// blocks 2048..10239: k3 base (pure HBM streaming) -- overlaps encoder latency
__global__ __launch_bounds__(256) void k13(
    const float* __restrict__ xd, const float* __restrict__ xs,
    const float* __restrict__ Wd, const float* __restrict__ bd,
    const float* __restrict__ Ws, const float* __restrict__ bs,
    const float* __restrict__ Wf, const float* __restrict__ bf,
    const float* __restrict__ Wq, const float* __restrict__ Wk,
    unsigned short* __restrict__ qh, unsigned short* __restrict__ kh,
    const float* __restrict__ prior, float* __restrict__ Lout,
    float* __restrict__ Aout)
{
    if (blockIdx.x >= NR/4) {
        // ---- k3 body: A = 0.3*prior; L = -A; 0.3*rowsum -> diagonal
        int r = blockIdx.x - NR/4;
        __shared__ float wsum[4];
        const float4* pr = (const float4*)(prior + (size_t)r * NN);
        float4* Ar = (float4*)(Aout + (size_t)r * NN);
        float4* Lr = (float4*)(Lout + (size_t)r * NN);
        float sum = 0.f;
        for (int i = threadIdx.x; i < NN/4; i += 256) {
            float4 p = pr[i];
            float4 a; a.x = 0.3f*p.x; a.y = 0.3f*p.y; a.z = 0.3f*p.z; a.w = 0.3f*p.w;
            Ar[i] = a;
            float4 lv; lv.x = -a.x; lv.y = -a.y; lv.z = -a.z; lv.w = -a.w;
            Lr[i] = lv;
            sum += a.x + a.y + a.z + a.w;
        }
        #pragma unroll
        for (int o = 32; o > 0; o >>= 1) sum += __shfl_down(sum, o);
        if ((threadIdx.x & 63) == 0) wsum[threadIdx.x >> 6] = sum;
        __syncthreads();
        if (threadIdx.x == 0) {
            float tot = wsum[0] + wsum[1] + wsum[2] + wsum[3];
            atomicAdd(&Lout[(size_t)r * NN + (r & 2047)], tot);
        }
        return;
    }

    // ---- k1 body: encoders + fusion + q/k projection (bf16, dense 16-dim)
    int wave = threadIdx.x >> 6;
    int lane = threadIdx.x & 63;
    int r = blockIdx.x * 4 + wave;        // 0..8191

    __shared__ float xm[4][16];
    __shared__ float xst[4][8];
    __shared__ float hc[4][128];
    __shared__ float hh[4][64];

    const float* xdr = xd + (size_t)r * 512;
    float acc = 0.f;
    #pragma unroll
    for (int j = 0; j < 8; ++j) acc += xdr[lane + 64*j];
    acc += __shfl_xor(acc, 16);
    acc += __shfl_xor(acc, 32);
    if (lane < 16) xm[wave][lane] = acc * (1.0f/32.0f);
    if (lane < 8)  xst[wave][lane] = xs[(size_t)r*8 + lane];
    __syncthreads();

    float a1 = bd[lane];
    #pragma unroll
    for (int d = 0; d < 16; ++d) a1 += xm[wave][d] * Wd[d*64 + lane];
    a1 = fmaxf(a1, 0.f);
    float a2 = bs[lane];
    #pragma unroll
    for (int d = 0; d < 8; ++d) a2 += xst[wave][d] * Ws[d*64 + lane];
    a2 = fmaxf(a2, 0.f);
    hc[wave][lane] = a1;
    hc[wave][64 + lane] = a2;
    __syncthreads();

    // 4 accumulators: break the 128-long fma dependency chain
    float hv0 = bf[lane], hv1 = 0.f, hv2 = 0.f, hv3 = 0.f;
    #pragma unroll
    for (int j = 0; j < 128; j += 4) {
        hv0 += hc[wave][j]   * Wf[(j)*64   + lane];
        hv1 += hc[wave][j+1] * Wf[(j+1)*64 + lane];
        hv2 += hc[wave][j+2] * Wf[(j+2)*64 + lane];
        hv3 += hc[wave][j+3] * Wf[(j+3)*64 + lane];
    }
    hh[wave][lane] = (hv0 + hv1) + (hv2 + hv3);
    __syncthreads();

    float qv0 = 0.f, qv1 = 0.f, kv0 = 0.f, kv1 = 0.f;
    #pragma unroll
    for (int j = 0; j < 64; j += 2) {
        float h0 = hh[wave][j], h1 = hh[wave][j+1];
        qv0 += h0 * Wq[(j)*64   + lane];
        qv1 += h1 * Wq[(j+1)*64 + lane];
        kv0 += h0 * Wk[(j)*64   + lane];
        kv1 += h1 * Wk[(j+1)*64 + lane];
    }
    float qv = qv0 + qv1, kv = kv0 + kv1;
    // lane = head*16 + dim; dense layout qh[(b*4+h)*2048 + n][16]
    int b = r >> 11, n = r & 2047;
    int head = lane >> 4, dim = lane & 15;
    size_t base = ((size_t)(b*4 + head) * NN + n) * 16;
    qh[base + dim] = f2bf(qv);
    kh[base + dim] = f2bf(kv);
}

// ---------------- K2: fused denominators + values + register top-10 + scatter
// Swapped operands (A=K-tile, B=Q-tile) -> q-row = lane&31. No max machinery
// (scores ~N(0,1); exp2(s*0.25*log2e) cannot overflow -- validated rounds 2-6).
// Phase 2 selects per-lane top-10 candidates IN REGISTERS during the value
// sweep (no 131KB vt staging, no full-row re-scan); phase 3 merges 320
// pre-sorted candidates (5/lane, sorted by construction: each source list of
// 10 splits 5/5 preserving order, and no merge lane can own >5 of the top-10).
__global__ __launch_bounds__(1024, 4) void k2_fused(
    const unsigned short* __restrict__ qh, const unsigned short* __restrict__ kh,
    float* __restrict__ Lout, float* __restrict__ Aout)
{
    const float C1 = 0.36067376022224085f;   // 0.25 * log2(e)
    int b  = blockIdx.x >> 6;
    int rg = blockIdx.x & 63;                // row group of 32
    int tid = threadIdx.x;
    int w = tid >> 6, l = tid & 63;
    int row = l & 31, khalf = l >> 5;

    __shared__ unsigned cand[32 * CSTRIDE];  // [row][32 lists * 10 keys] 41KB
    __shared__ float redS[16][4][32];        // [wave][head][row] partials 8KB
    __shared__ float r4s[4][32];             // [head][row] 0.25/S

    bf16x8 qfrag[4];
    #pragma unroll
    for (int h = 0; h < 4; ++h)
        qfrag[h] = *(const bf16x8*)(qh + ((size_t)(b*4+h) * NN + rg*32 + row) * 16 + khalf*8);

    // ---- phase 0: per-(head,row) exp-sums; wave strip = 128 cols (4 tiles)
    float Sl[4] = {0.f, 0.f, 0.f, 0.f};
    for (int t = 0; t < 4; ++t) {
        int m0 = w*128 + t*32;
        #pragma unroll
        for (int h = 0; h < 4; ++h) {
            bf16x8 kfrag = *(const bf16x8*)(kh + ((size_t)(b*4+h) * NN + m0 + row) * 16 + khalf*8);
            f32x16 acc = {0.f,0.f,0.f,0.f,0.f,0.f,0.f,0.f,0.f,0.f,0.f,0.f,0.f,0.f,0.f,0.f};
            acc = __builtin_amdgcn_mfma_f32_32x32x16_bf16(kfrag, qfrag[h], acc, 0, 0, 0);
            #pragma unroll
            for (int rr = 0; rr < 16; ++rr) Sl[h] += exp2f(acc[rr] * C1);
        }
    }
    #pragma unroll
    for (int h = 0; h < 4; ++h) Sl[h] += __shfl_xor(Sl[h], 32);  // merge khalf halves
    if (l < 32) {
        #pragma unroll
        for (int h = 0; h < 4; ++h) redS[w][h][l] = Sl[h];
    }
    __syncthreads();
    if (tid < 128) {
        int h = tid >> 5, rw = tid & 31;
        float s = 0.f;
        #pragma unroll
        for (int ww = 0; ww < 16; ++ww) s += redS[ww][h][rw];
        r4s[h][rw] = 0.25f / s;
    }
    __syncthreads();

    float r4[4];
    #pragma unroll
    for (int h = 0; h < 4; ++h) r4[h] = r4s[h][row];

    // ---- phase 2: combined values + per-lane top-10 in registers
    // keys packed u32: (bf16_value << 16) | (2047 - col)  [lossless order]
    unsigned tkl[TOPK];
    #pragma unroll
    for (int s = 0; s < TOPK; ++s) tkl[s] = 0u;
    for (int t = 0; t < 4; ++t) {
        int m0 = w*128 + t*32;
        float vacc[16];
        #pragma unroll
        for (int rr = 0; rr < 16; ++rr) vacc[rr] = 0.f;
        #pragma unroll
        for (int h = 0; h < 4; ++h) {
            bf16x8 kfrag = *(const bf16x8*)(kh + ((size_t)(b*4+h) * NN + m0 + row) * 16 + khalf*8);
            f32x16 acc = {0.f,0.f,0.f,0.f,0.f,0.f,0.f,0.f,0.f,0.f,0.f,0.f,0.f,0.f,0.f,0.f};
            acc = __builtin_amdgcn_mfma_f32_32x32x16_bf16(kfrag, qfrag[h], acc, 0, 0, 0);
            #pragma unroll
            for (int rr = 0; rr < 16; ++rr)
                vacc[rr] = fmaf(exp2f(acc[rr] * C1), r4[h], vacc[rr]);
        }
        // col of reg rr: c = m0 + (rr&3) + 8*(rr>>2) + 4*khalf
        #pragma unroll
        for (int rr = 0; rr < 16; ++rr) {
            int c = m0 + ((rr & 3) + 8*(rr >> 2) + 4*khalf);
            unsigned key = ((unsigned)f2bf(vacc[rr]) << 16) | (unsigned)(2047 - c);
            if (key > tkl[TOPK-1]) {
                unsigned ck = key;
                #pragma unroll
                for (int s = 0; s < TOPK; ++s) {
                    bool ins = ck > tkl[s];
                    unsigned o = tkl[s];
                    tkl[s] = ins ? ck : o;
                    ck     = ins ? o  : ck;
                }
            }
        }
    }
    {
        unsigned* cr = &cand[row * CSTRIDE + (w*2 + khalf) * TOPK];
        #pragma unroll
        for (int s = 0; s < TOPK; ++s) cr[s] = tkl[s];
    }
    __syncthreads();

    // ---- phase 3: merge 320 sorted candidates -> top-10; 2 rows per wave
    #pragma unroll 1
    for (int rr2 = 0; rr2 < 2; ++rr2) {
        int prow = w*2 + rr2;
        const unsigned* flat = &cand[prow * CSTRIDE];
        unsigned tk5[5];
        #pragma unroll
        for (int i = 0; i < 5; ++i) tk5[i] = flat[l*5 + i];  // already sorted desc
        unsigned mykey = 0u;
        #pragma unroll 1
        for (int s = 0; s < TOPK; ++s) {
            unsigned kmax = tk5[0];
            #pragma unroll
            for (int d = 1; d < 64; d <<= 1) {
                unsigned o = __shfl_xor(kmax, d);
                kmax = (o > kmax) ? o : kmax;
            }
            if (tk5[0] == kmax) {  // exactly one winner pops its head
                #pragma unroll
                for (int q = 0; q < 4; ++q) tk5[q] = tk5[q+1];
                tk5[4] = 0u;
            }
            if (l == s) mykey = kmax;
        }

        // ---- phase 4: symmetric scatter; own-diag pre-reduced to ONE atomic
        int n = rg*32 + prow;
        size_t rbase = (size_t)(b*NN + n) * NN;
        float wv = 0.f;
        int j = 0;
        if (l < TOPK) {
            wv = 0.35f * __uint_as_float(mykey & 0xFFFF0000u);  // 0.7*0.5*val
            j = 2047 - (int)(mykey & 0x7FFu);
        }
        float swv = wv;
        #pragma unroll
        for (int d = 1; d <= 8; d <<= 1) swv += __shfl_xor(swv, d);
        if (l == 0) atomicAdd(&Lout[rbase + n], swv);   // deg[r] -> diag r
        if (l < TOPK) {
            size_t jbase = (size_t)(b*NN + j) * NN;
            atomicAdd(&Aout[rbase + j],  wv);
            atomicAdd(&Aout[jbase + n],  wv);
            atomicAdd(&Lout[rbase + j], -wv);
            atomicAdd(&Lout[jbase + n], -wv);
            atomicAdd(&Lout[jbase + j],  wv);           // deg[j] -> diag j
        }
    }
}

extern "C" void kernel_launch(void* const* d_in, const int* in_sizes, int n_in,
                              void* d_out, int out_size, void* d_ws, size_t ws_size,
                              hipStream_t stream)
{
    const float* xd    = (const float*)d_in[0];
    const float* xs    = (const float*)d_in[1];
    const float* prior = (const float*)d_in[2];
    const float* Wd    = (const float*)d_in[3];
    const float* bd    = (const float*)d_in[4];
    const float* Ws    = (const float*)d_in[5];
    const float* bs    = (const float*)d_in[6];
    const float* Wf    = (const float*)d_in[7];
    const float* bf    = (const float*)d_in[8];
    const float* Wq    = (const float*)d_in[9];
    const float* Wk    = (const float*)d_in[10];

    float* Lout = (float*)d_out;
    float* Aout = Lout + (size_t)NR * NN;

    unsigned short* qh = (unsigned short*)d_ws;          // 16*2048*16 bf16 = 1MB
    unsigned short* kh = qh + (size_t)16 * NN * 16;      // 1MB

    k13<<<NR/4 + NR, 256, 0, stream>>>(xd, xs, Wd, bd, Ws, bs, Wf, bf, Wq, Wk,
                                       qh, kh, prior, Lout, Aout);
    k2_fused<<<NBATCH*64, 1024, 0, stream>>>(qh, kh, Lout, Aout);
}

// Round 9
// 302.996 us; speedup vs baseline: 1.0695x; 1.0695x over previous
//
#include <hip/hip_runtime.h>

#define NBATCH 4
#define NN 2048
#define NR 8192            // NBATCH*NN rows
#define TOPK 10
#define CSTRIDE 161        // cand row stride in words (16 lists * 10 + 1, odd)

typedef __attribute__((ext_vector_type(16))) float f32x16;
typedef __attribute__((ext_vector_type(8))) short bf16x8;

__device__ inline unsigned short f2bf(float x) {
    unsigned u = __float_as_uint(x);
    unsigned r = (u + 0x7FFF + ((u >> 16) & 1)) >> 16;
    return (unsigned short)r;
}

// ---------------- K1: encoders + fusion + q/k projection (bf16, dense 16-dim)
__global__ __launch_bounds__(256) void k1_encode(
    const float* __restrict__ xd, const float* __restrict__ xs,
    const float* __restrict__ Wd, const float* __restrict__ bd,
    const float* __restrict__ Ws, const float* __restrict__ bs,
    const float* __restrict__ Wf, const float* __restrict__ bf,
    const float* __restrict__ Wq, const float* __restrict__ Wk,
    unsigned short* __restrict__ qh, unsigned short* __restrict__ kh)
{
    int wave = threadIdx.x >> 6;
    int lane = threadIdx.x & 63;
    int r = blockIdx.x * 4 + wave;        // 0..8191

    __shared__ float xm[4][16];
    __shared__ float xst[4][8];
    __shared__ float hc[4][128];
    __shared__ float hh[4][64];

    const float* xdr = xd + (size_t)r * 512;
    float acc = 0.f;
    #pragma unroll
    for (int j = 0; j < 8; ++j) acc += xdr[lane + 64*j];
    acc += __shfl_xor(acc, 16);
    acc += __shfl_xor(acc, 32);
    if (lane < 16) xm[wave][lane] = acc * (1.0f/32.0f);
    if (lane < 8)  xst[wave][lane] = xs[(size_t)r*8 + lane];
    __syncthreads();

    float a1 = bd[lane];
    #pragma unroll
    for (int d = 0; d < 16; ++d) a1 += xm[wave][d] * Wd[d*64 + lane];
    a1 = fmaxf(a1, 0.f);
    float a2 = bs[lane];
    #pragma unroll
    for (int d = 0; d < 8; ++d) a2 += xst[wave][d] * Ws[d*64 + lane];
    a2 = fmaxf(a2, 0.f);
    hc[wave][lane] = a1;
    hc[wave][64 + lane] = a2;
    __syncthreads();

    float hv0 = bf[lane], hv1 = 0.f, hv2 = 0.f, hv3 = 0.f;
    #pragma unroll
    for (int j = 0; j < 128; j += 4) {
        hv0 += hc[wave][j]   * Wf[(j)*64   + lane];
        hv1 += hc[wave][j+1] * Wf[(j+1)*64 + lane];
        hv2 += hc[wave][j+2] * Wf[(j+2)*64 + lane];
        hv3 += hc[wave][j+3] * Wf[(j+3)*64 + lane];
    }
    hh[wave][lane] = (hv0 + hv1) + (hv2 + hv3);
    __syncthreads();

    float qv0 = 0.f, qv1 = 0.f, kv0 = 0.f, kv1 = 0.f;
    #pragma unroll
    for (int j = 0; j < 64; j += 2) {
        float h0 = hh[wave][j], h1 = hh[wave][j+1];
        qv0 += h0 * Wq[(j)*64   + lane];
        qv1 += h1 * Wq[(j+1)*64 + lane];
        kv0 += h0 * Wk[(j)*64   + lane];
        kv1 += h1 * Wk[(j+1)*64 + lane];
    }
    float qv = qv0 + qv1, kv = kv0 + kv1;
    int b = r >> 11, n = r & 2047;
    int head = lane >> 4, dim = lane & 15;
    size_t base = ((size_t)(b*4 + head) * NN + n) * 16;
    qh[base + dim] = f2bf(qv);
    kh[base + dim] = f2bf(kv);
}

// ---------------- K23: co-scheduled k2-compute (blocks 0..255) + k3-stream --
// k2-compute: softmax denominators + head-avg values + exact top-10 -> winners
// (u32 keys) + pre-reduced degree weight per row. NEVER touches L/A.
// k3: A = 0.3*prior; L = -A; 0.3*rowsum -> diagonal. Pure HBM streaming.
// Both 512-thr, <=128 VGPR (launch_bounds 512,4) -> one k2 block (8 waves,
// ~25KB LDS) and one k3 block co-reside per CU: compute overlaps streaming.
__global__ __launch_bounds__(512, 4) void k23(
    const unsigned short* __restrict__ qh, const unsigned short* __restrict__ kh,
    unsigned* __restrict__ winners, float* __restrict__ diagw,
    const float* __restrict__ prior, float* __restrict__ Lout,
    float* __restrict__ Aout)
{
    const float C1 = 0.36067376022224085f;   // 0.25 * log2(e)
    int tid = threadIdx.x;

    if (blockIdx.x >= 256) {
        // ---- k3 body: one row per block, 512 float4 lanes
        int r = blockIdx.x - 256;
        __shared__ float wsum[8];
        const float4* pr = (const float4*)(prior + (size_t)r * NN);
        float4* Ar = (float4*)(Aout + (size_t)r * NN);
        float4* Lr = (float4*)(Lout + (size_t)r * NN);
        float4 p = pr[tid];
        float4 a; a.x = 0.3f*p.x; a.y = 0.3f*p.y; a.z = 0.3f*p.z; a.w = 0.3f*p.w;
        Ar[tid] = a;
        float4 lv; lv.x = -a.x; lv.y = -a.y; lv.z = -a.z; lv.w = -a.w;
        Lr[tid] = lv;
        float sum = a.x + a.y + a.z + a.w;
        #pragma unroll
        for (int o = 32; o > 0; o >>= 1) sum += __shfl_down(sum, o);
        if ((tid & 63) == 0) wsum[tid >> 6] = sum;
        __syncthreads();
        if (tid == 0) {
            float tot = 0.f;
            #pragma unroll
            for (int ww = 0; ww < 8; ++ww) tot += wsum[ww];
            atomicAdd(&Lout[(size_t)r * NN + (r & 2047)], tot);
        }
        return;
    }

    // ---- k2-compute body: 8 waves, 32 rows, 256-col strip per wave
    int b  = blockIdx.x >> 6;
    int rg = blockIdx.x & 63;                // row group of 32
    int w = tid >> 6, l = tid & 63;
    int row = l & 31, khalf = l >> 5;

    __shared__ unsigned cand[32 * CSTRIDE];  // [row][16 lists * 10 keys] ~20.6KB
    __shared__ float redS[8][4][32];         // [wave][head][row] partials 4KB
    __shared__ float r4s[4][32];             // [head][row] 0.25/S

    bf16x8 qfrag[4];
    #pragma unroll
    for (int h = 0; h < 4; ++h)
        qfrag[h] = *(const bf16x8*)(qh + ((size_t)(b*4+h) * NN + rg*32 + row) * 16 + khalf*8);

    // ---- phase 0: per-(head,row) exp-sums; 8 tiles per wave strip
    // No max machinery: scores ~N(0,1); exp2(s*0.25*log2e) cannot overflow
    // (validated passing rounds 2-7).
    float Sl[4] = {0.f, 0.f, 0.f, 0.f};
    for (int t = 0; t < 8; ++t) {
        int m0 = w*256 + t*32;
        #pragma unroll
        for (int h = 0; h < 4; ++h) {
            bf16x8 kfrag = *(const bf16x8*)(kh + ((size_t)(b*4+h) * NN + m0 + row) * 16 + khalf*8);
            f32x16 acc = {0.f,0.f,0.f,0.f,0.f,0.f,0.f,0.f,0.f,0.f,0.f,0.f,0.f,0.f,0.f,0.f};
            acc = __builtin_amdgcn_mfma_f32_32x32x16_bf16(kfrag, qfrag[h], acc, 0, 0, 0);
            #pragma unroll
            for (int rr = 0; rr < 16; ++rr) Sl[h] += exp2f(acc[rr] * C1);
        }
    }
    #pragma unroll
    for (int h = 0; h < 4; ++h) Sl[h] += __shfl_xor(Sl[h], 32);  // merge khalf halves
    if (l < 32) {
        #pragma unroll
        for (int h = 0; h < 4; ++h) redS[w][h][l] = Sl[h];
    }
    __syncthreads();
    if (tid < 128) {
        int h = tid >> 5, rw = tid & 31;
        float s = 0.f;
        #pragma unroll
        for (int ww = 0; ww < 8; ++ww) s += redS[ww][h][rw];
        r4s[h][rw] = 0.25f / s;
    }
    __syncthreads();

    float r4[4];
    #pragma unroll
    for (int h = 0; h < 4; ++h) r4[h] = r4s[h][row];

    // ---- phase 2: combined values + per-lane top-10 in registers
    // keys packed u32: (bf16_value << 16) | (2047 - col)  [lossless order]
    unsigned tkl[TOPK];
    #pragma unroll
    for (int s = 0; s < TOPK; ++s) tkl[s] = 0u;
    for (int t = 0; t < 8; ++t) {
        int m0 = w*256 + t*32;
        float vacc[16];
        #pragma unroll
        for (int rr = 0; rr < 16; ++rr) vacc[rr] = 0.f;
        #pragma unroll
        for (int h = 0; h < 4; ++h) {
            bf16x8 kfrag = *(const bf16x8*)(kh + ((size_t)(b*4+h) * NN + m0 + row) * 16 + khalf*8);
            f32x16 acc = {0.f,0.f,0.f,0.f,0.f,0.f,0.f,0.f,0.f,0.f,0.f,0.f,0.f,0.f,0.f,0.f};
            acc = __builtin_amdgcn_mfma_f32_32x32x16_bf16(kfrag, qfrag[h], acc, 0, 0, 0);
            #pragma unroll
            for (int rr = 0; rr < 16; ++rr)
                vacc[rr] = fmaf(exp2f(acc[rr] * C1), r4[h], vacc[rr]);
        }
        // col of reg rr: c = m0 + (rr&3) + 8*(rr>>2) + 4*khalf
        #pragma unroll
        for (int rr = 0; rr < 16; ++rr) {
            int c = m0 + ((rr & 3) + 8*(rr >> 2) + 4*khalf);
            unsigned key = ((unsigned)f2bf(vacc[rr]) << 16) | (unsigned)(2047 - c);
            if (key > tkl[TOPK-1]) {
                unsigned ck = key;
                #pragma unroll
                for (int s = 0; s < TOPK; ++s) {
                    bool ins = ck > tkl[s];
                    unsigned o = tkl[s];
                    tkl[s] = ins ? ck : o;
                    ck     = ins ? o  : ck;
                }
            }
        }
    }
    {
        unsigned* cr = &cand[row * CSTRIDE + (w*2 + khalf) * TOPK];
        #pragma unroll
        for (int s = 0; s < TOPK; ++s) cr[s] = tkl[s];
    }
    __syncthreads();

    // ---- phase 3: merge 160 candidates -> top-10; 4 rows per wave.
    // Lane l holds flat keys {l, l+64, l+128(<160)}; 3-elem descending sort
    // restores the pop-head invariant. Partition => each candidate on exactly
    // one lane; 10 argmax-with-removal rounds extract the exact top-10.
    #pragma unroll 1
    for (int rr2 = 0; rr2 < 4; ++rr2) {
        int prow = w*4 + rr2;
        const unsigned* flat = &cand[prow * CSTRIDE];
        unsigned t0 = flat[l];
        unsigned t1 = flat[l + 64];
        unsigned t2 = (l < 32) ? flat[l + 128] : 0u;
        // sort descending (3 compare-swaps)
        if (t1 > t0) { unsigned x = t0; t0 = t1; t1 = x; }
        if (t2 > t1) { unsigned x = t1; t1 = t2; t2 = x; }
        if (t1 > t0) { unsigned x = t0; t0 = t1; t1 = x; }
        unsigned mykey = 0u;
        #pragma unroll 1
        for (int s = 0; s < TOPK; ++s) {
            unsigned kmax = t0;
            #pragma unroll
            for (int d = 1; d < 64; d <<= 1) {
                unsigned o = __shfl_xor(kmax, d);
                kmax = (o > kmax) ? o : kmax;
            }
            if (t0 == kmax) { t0 = t1; t1 = t2; t2 = 0u; }  // winner pops head
            if (l == s) mykey = kmax;
        }

        // ---- emit: winners + pre-reduced degree weight (no L/A access here)
        int n = rg*32 + prow;
        int r = b*NN + n;
        float wv = (l < TOPK) ? 0.35f * __uint_as_float(mykey & 0xFFFF0000u) : 0.f;
        float swv = wv;
        #pragma unroll
        for (int d = 1; d <= 8; d <<= 1) swv += __shfl_xor(swv, d);
        if (l == 0) diagw[r] = swv;
        if (l < TOPK) winners[(size_t)l * NR + r] = mykey;
    }
}

// ---------------- K4: scatter symmetric sparse top-k from winner keys -------
// one thread per (s, r): coalesced loads, fire-and-forget atomics.
__global__ __launch_bounds__(256) void k4_scatter(
    const unsigned* __restrict__ winners, const float* __restrict__ diagw,
    float* __restrict__ Lout, float* __restrict__ Aout)
{
    int wk = blockIdx.x * 256 + threadIdx.x;   // 0..81919
    int s = wk >> 13;                           // 0..9
    int r = wk & 8191;                          // 0..8191
    int b = r >> 11;
    int n = r & 2047;
    unsigned key = winners[(size_t)s * NR + r];
    float wv = 0.35f * __uint_as_float(key & 0xFFFF0000u);  // 0.7 * 0.5 * val
    int j = 2047 - (int)(key & 0x7FFu);
    size_t rbase = (size_t)r * NN;
    size_t jbase = (size_t)(b * NN + j) * NN;
    atomicAdd(&Aout[rbase + j],  wv);
    atomicAdd(&Aout[jbase + n],  wv);
    atomicAdd(&Lout[rbase + j], -wv);
    atomicAdd(&Lout[jbase + n], -wv);
    atomicAdd(&Lout[jbase + j],  wv);              // deg[j] -> diag j
    if (s == 0) atomicAdd(&Lout[rbase + n], diagw[r]);  // deg[r] -> diag r
}

extern "C" void kernel_launch(void* const* d_in, const int* in_sizes, int n_in,
                              void* d_out, int out_size, void* d_ws, size_t ws_size,
                              hipStream_t stream)
{
    const float* xd    = (const float*)d_in[0];
    const float* xs    = (const float*)d_in[1];
    const float* prior = (const float*)d_in[2];
    const float* Wd    = (const float*)d_in[3];
    const float* bd    = (const float*)d_in[4];
    const float* Ws    = (const float*)d_in[5];
    const float* bs    = (const float*)d_in[6];
    const float* Wf    = (const float*)d_in[7];
    const float* bf    = (const float*)d_in[8];
    const float* Wq    = (const float*)d_in[9];
    const float* Wk    = (const float*)d_in[10];

    float* Lout = (float*)d_out;
    float* Aout = Lout + (size_t)NR * NN;

    unsigned short* qh = (unsigned short*)d_ws;              // 16*2048*16 bf16 = 1MB
    unsigned short* kh = qh + (size_t)16 * NN * 16;          // 1MB
    unsigned* winners  = (unsigned*)(kh + (size_t)16 * NN * 16);  // 10*8192 u32
    float* diagw       = (float*)(winners + (size_t)TOPK * NR);   // 8192 f32

    k1_encode<<<NR/4, 256, 0, stream>>>(xd, xs, Wd, bd, Ws, bs, Wf, bf, Wq, Wk, qh, kh);
    k23<<<256 + NR, 512, 0, stream>>>(qh, kh, winners, diagw, prior, Lout, Aout);
    k4_scatter<<<TOPK*NR/256, 256, 0, stream>>>(winners, diagw, Lout, Aout);
}